// Round 22
// baseline (675.844 us; speedup 1.0000x reference)
//
#include <hip/hip_runtime.h>
#include <hip/hip_bf16.h>
#include <cstddef>

// ---------------------------------------------------------------------------
// EncoderModule: 5x causal conv1d (K=7) + ELU, then 2x VQ argmin (1024 codes, D=64)
// B=64, L=48000, strides 2,2,2,3,1; channels 1->16->32->64->64->128
// Output: int32 indices, shape (2, 64, 2000)
//
// conv0 fused into conv1 (bit-identical H0 recompute). convs 2-4: 6-term
// split3-bf16 MFMA, fp32 t-major I/O. r22: conv2/conv4 use NT=64 tiles
// (LDS ~26KB -> 4-5 blocks/CU; was 2 at ~51KB — latency-bound fix).
// VQ: -2c codebook, ||c||^2 in accumulator init, med3 best/second, 2x16KB
// double-buffered chunks, waves_per_eu(4,4). gap<0.04 -> flag; 4-way rescore.
// ---------------------------------------------------------------------------

using bf16x8 = __attribute__((ext_vector_type(8))) short;
using s16x4  = __attribute__((ext_vector_type(4))) short;
using f32x4  = __attribute__((ext_vector_type(4))) float;

static __device__ __forceinline__ short f2bf(float f) {
    __hip_bfloat16 h = __float2bfloat16(f);   // RNE
    union { __hip_bfloat16 h; short s; } u; u.h = h;
    return u.s;
}
static __device__ __forceinline__ float bf2f(short s) {
    union { unsigned u; float f; } v;
    v.u = ((unsigned)(unsigned short)s) << 16;
    return v.f;
}
static __device__ __forceinline__ void split3(float v, short& s0, short& s1, short& s2) {
    s0 = f2bf(v);  float r1 = v  - bf2f(s0);   // exact
    s1 = f2bf(r1); float r2 = r1 - bf2f(s1);   // exact
    s2 = f2bf(r2);                             // residual ~2^-24 |v|
}
static __device__ __forceinline__ float elu(float v) {
    return v > 0.0f ? v : expm1f(v);
}

// ---------------- fused conv0+conv1 -----------------------------------------
__global__ __launch_bounds__(256) void conv01_kernel(
    const float* __restrict__ x, const float* __restrict__ w0,
    const float* __restrict__ b0, const short* __restrict__ wfrag,
    const float* __restrict__ bias, float* __restrict__ Hout)
{
    constexpr int CIN = 32, COUT = 32, NTL = 2, TAPS = 4, S = 1;
    constexpr int KC = 1, MT = 2, NT = 128, ROWS = 131, ROWB = 64;
    constexpr int Lin = 12000, Lout = 12000;
    __shared__ __align__(16) short pl0[ROWS * CIN];
    __shared__ __align__(16) short pl1[ROWS * CIN];
    __shared__ __align__(16) short pl2[ROWS * CIN];
    __shared__ float xs[536];

    int nb = blockIdx.x, b = blockIdx.y;
    int t0 = nb * NT;
    int tid = threadIdx.x, lane = tid & 63, wv = tid >> 6;
    int g0 = t0 - 3;                      // first H0 row (u) in the tile

    const float* xb = x + (size_t)b * 48000;
    int xbase = 4 * g0 - 6;
    for (int i = tid; i < 529; i += 256) {
        int g = xbase + i;
        xs[i] = (g >= 0 && g < 48000) ? xb[g] : 0.0f;
    }
    __syncthreads();

    for (int e = tid; e < ROWS * 8; e += 256) {
        int rr = e >> 3, sl = e & 7;
        int g = g0 + rr;
        int ph = sl >> 2;
        int xr = (rr >> 1) & 3;           // CIN==32 swizzle
        int byte = rr * ROWB + ((((sl >> 1) ^ xr) << 4) | ((sl & 1) << 3));
        bool ok = (g >= 0 && g < Lin);
        int bx = 4 * rr + 2 * ph;
        s16x4 q0, q1, q2;
        #pragma unroll
        for (int j = 0; j < 4; ++j) {
            float v = 0.0f;
            if (ok) {
                int co = (sl & 3) * 4 + j;
                const float* wp = w0 + co * 7;
                float acc = 0.f;
                #pragma unroll
                for (int k = 0; k < 7; ++k)
                    acc = fmaf(wp[k], xs[bx + k], acc);
                v = elu(acc + b0[co]);
            }
            short a0, a1, a2;
            split3(v, a0, a1, a2);
            q0[j] = a0; q1[j] = a1; q2[j] = a2;
        }
        *(s16x4*)((char*)pl0 + byte) = q0;
        *(s16x4*)((char*)pl1 + byte) = q1;
        *(s16x4*)((char*)pl2 + byte) = q2;
    }
    __syncthreads();

    f32x4 acc[NTL][MT];
    #pragma unroll
    for (int n = 0; n < NTL; ++n)
        #pragma unroll
        for (int m = 0; m < MT; ++m) acc[n][m] = (f32x4){0.f, 0.f, 0.f, 0.f};

    int ncol = lane & 15, nq = lane >> 4;

    for (int k = 0; k < TAPS; ++k) {
        #pragma unroll
        for (int kc = 0; kc < KC; ++kc) {
            int colb = (kc * 32 + nq * 8) * 2;
            bf16x8 B0[NTL], B1[NTL], B2[NTL];
            #pragma unroll
            for (int ntl = 0; ntl < NTL; ++ntl) {
                int r  = S * ((wv * NTL + ntl) * 16 + ncol) + k;
                int xr = (r >> 1) & 3;
                int byte = r * ROWB + (colb ^ (xr << 4));
                B0[ntl] = *(const bf16x8*)((char*)pl0 + byte);
                B1[ntl] = *(const bf16x8*)((char*)pl1 + byte);
                B2[ntl] = *(const bf16x8*)((char*)pl2 + byte);
            }
            #pragma unroll
            for (int m = 0; m < MT; ++m) {
                size_t base = ((size_t)(m * KC + kc) * TAPS + k) * 3;
                bf16x8 a0 = *(const bf16x8*)(wfrag + (base + 0) * 512 + lane * 8);
                bf16x8 a1 = *(const bf16x8*)(wfrag + (base + 1) * 512 + lane * 8);
                bf16x8 a2 = *(const bf16x8*)(wfrag + (base + 2) * 512 + lane * 8);
                #pragma unroll
                for (int ntl = 0; ntl < NTL; ++ntl) {
                    f32x4 a = acc[ntl][m];
                    a = __builtin_amdgcn_mfma_f32_16x16x32_bf16(a0, B0[ntl], a, 0, 0, 0);
                    a = __builtin_amdgcn_mfma_f32_16x16x32_bf16(a1, B0[ntl], a, 0, 0, 0);
                    a = __builtin_amdgcn_mfma_f32_16x16x32_bf16(a2, B0[ntl], a, 0, 0, 0);
                    a = __builtin_amdgcn_mfma_f32_16x16x32_bf16(a0, B1[ntl], a, 0, 0, 0);
                    a = __builtin_amdgcn_mfma_f32_16x16x32_bf16(a1, B1[ntl], a, 0, 0, 0);
                    a = __builtin_amdgcn_mfma_f32_16x16x32_bf16(a0, B2[ntl], a, 0, 0, 0);
                    acc[ntl][m] = a;
                }
            }
        }
    }

    #pragma unroll
    for (int ntl = 0; ntl < NTL; ++ntl) {
        int n = t0 + (wv * NTL + ntl) * 16 + ncol;
        if (n < Lout) {
            #pragma unroll
            for (int m = 0; m < MT; ++m) {
                int co0 = m * 16 + nq * 4;
                float4 bb = *(const float4*)(bias + co0);
                float4 vv;
                vv.x = elu(acc[ntl][m][0] + bb.x);
                vv.y = elu(acc[ntl][m][1] + bb.y);
                vv.z = elu(acc[ntl][m][2] + bb.z);
                vv.w = elu(acc[ntl][m][3] + bb.w);
                *(float4*)(Hout + ((size_t)b * (Lout >> 1) + (n >> 1)) * (2 * COUT)
                           + (n & 1) * COUT + co0) = vv;
            }
        }
    }
}

// ---------------- weight prep: 3-level bf16 A-fragments ---------------------
template<int CIN, int COUT, int TAPS>
__global__ void wprep3_kernel(const float* __restrict__ w, short* __restrict__ frag)
{
    constexpr int KC = CIN / 32;
    int co = threadIdx.x;
    if (co >= COUT) return;
    int mt = co >> 4, nc = co & 15;
    for (int kc = 0; kc < KC; ++kc)
        for (int k = 0; k < TAPS; ++k)
            #pragma unroll
            for (int lh = 0; lh < 4; ++lh) {
                bf16x8 p0, p1, p2;
                #pragma unroll
                for (int j = 0; j < 8; ++j) {
                    int ci = kc * 32 + lh * 8 + j;
                    float f = w[(size_t)co * CIN * 7 + ci * 7 + k];
                    short a, bb, c; split3(f, a, bb, c);
                    p0[j] = a; p1[j] = bb; p2[j] = c;
                }
                size_t base = ((size_t)(mt * KC + kc) * TAPS + k) * 3;
                int off = (lh * 16 + nc) * 8;
                *(bf16x8*)(frag + (base + 0) * 512 + off) = p0;
                *(bf16x8*)(frag + (base + 1) * 512 + off) = p1;
                *(bf16x8*)(frag + (base + 2) * 512 + off) = p2;
            }
}

// phase-split packing (stride-2 K=7 -> stride-1 K=4 over doubled channels)
template<int CINH, int COUT>
__global__ void wprep3_ps_kernel(const float* __restrict__ w, short* __restrict__ frag)
{
    constexpr int CIN = 2 * CINH;
    constexpr int KC  = CIN / 32;
    int co = threadIdx.x;
    if (co >= COUT) return;
    int mt = co >> 4, nc = co & 15;
    for (int kc = 0; kc < KC; ++kc)
        for (int m = 0; m < 4; ++m)
            #pragma unroll
            for (int lh = 0; lh < 4; ++lh) {
                bf16x8 p0, p1, p2;
                #pragma unroll
                for (int j = 0; j < 8; ++j) {
                    int cp = kc * 32 + lh * 8 + j;
                    float f;
                    if (cp < CINH)  f = w[(size_t)co * CINH * 7 + cp * 7 + 2 * m];
                    else if (m < 3) f = w[(size_t)co * CINH * 7 + (cp - CINH) * 7 + 2 * m + 1];
                    else            f = 0.0f;
                    short a, bb, c; split3(f, a, bb, c);
                    p0[j] = a; p1[j] = bb; p2[j] = c;
                }
                size_t base = ((size_t)(mt * KC + kc) * 4 + m) * 3;
                int off = (lh * 16 + nc) * 8;
                *(bf16x8*)(frag + (base + 0) * 512 + off) = p0;
                *(bf16x8*)(frag + (base + 1) * 512 + off) = p1;
                *(bf16x8*)(frag + (base + 2) * 512 + off) = p2;
            }
}

// ---------------- conv via 6-term split3-bf16 MFMA, t-major fp32 I/O --------
template<int S, int CIN, int COUT, int NTL, int TAPS, int PAD, int OUTMODE, int WTILES>
__global__ __launch_bounds__(256) void conv_mfma3_kernel(
    const float* __restrict__ Hin, const short* __restrict__ wfrag,
    const float* __restrict__ bias, float* __restrict__ Hout,
    int Lin, int Lout)
{
    // WTILES = 16-row tiles per wave (NT = WTILES*... ): NT = 4 waves * NTL*16
    constexpr int KC   = CIN / 32;
    constexpr int MT   = COUT / 16;
    constexpr int NT   = NTL * 64;
    constexpr int ROWS = (NT - 1) * S + TAPS;
    constexpr int ROWB = CIN * 2;
    constexpr int NSL  = CIN / 4;
    __shared__ __align__(16) short pl0[ROWS * CIN];
    __shared__ __align__(16) short pl1[ROWS * CIN];
    __shared__ __align__(16) short pl2[ROWS * CIN];

    int nb = blockIdx.x, b = blockIdx.y;
    int t0 = nb * NT;
    int tid = threadIdx.x, lane = tid & 63, wv = tid >> 6;
    int g0 = t0 * S - PAD;

    const float* inb = Hin + (size_t)b * Lin * CIN;
    for (int e = tid; e < ROWS * NSL; e += 256) {
        int rr = e / NSL, sl = e % NSL;
        int g = g0 + rr;
        float4 v = {0.f, 0.f, 0.f, 0.f};
        if (g >= 0 && g < Lin)
            v = *(const float4*)(inb + (size_t)g * CIN + sl * 4);
        int xr = (CIN == 64) ? (rr & 7) : ((rr >> 1) & 3);
        int byte = rr * ROWB + ((((sl >> 1) ^ xr) << 4) | ((sl & 1) << 3));
        s16x4 q0, q1, q2;
        short a0, a1, a2;
        split3(v.x, a0, a1, a2); q0[0] = a0; q1[0] = a1; q2[0] = a2;
        split3(v.y, a0, a1, a2); q0[1] = a0; q1[1] = a1; q2[1] = a2;
        split3(v.z, a0, a1, a2); q0[2] = a0; q1[2] = a1; q2[2] = a2;
        split3(v.w, a0, a1, a2); q0[3] = a0; q1[3] = a1; q2[3] = a2;
        *(s16x4*)((char*)pl0 + byte) = q0;
        *(s16x4*)((char*)pl1 + byte) = q1;
        *(s16x4*)((char*)pl2 + byte) = q2;
    }
    __syncthreads();

    f32x4 acc[NTL][MT];
    #pragma unroll
    for (int n = 0; n < NTL; ++n)
        #pragma unroll
        for (int m = 0; m < MT; ++m) acc[n][m] = (f32x4){0.f, 0.f, 0.f, 0.f};

    int ncol = lane & 15, nq = lane >> 4;

    for (int k = 0; k < TAPS; ++k) {
        #pragma unroll
        for (int kc = 0; kc < KC; ++kc) {
            int colb = (kc * 32 + nq * 8) * 2;
            bf16x8 B0[NTL], B1[NTL], B2[NTL];
            #pragma unroll
            for (int ntl = 0; ntl < NTL; ++ntl) {
                int r  = S * ((wv * NTL + ntl) * 16 + ncol) + k;
                int xr = (CIN == 64) ? (r & 7) : ((r >> 1) & 3);
                int byte = r * ROWB + (colb ^ (xr << 4));
                B0[ntl] = *(const bf16x8*)((char*)pl0 + byte);
                B1[ntl] = *(const bf16x8*)((char*)pl1 + byte);
                B2[ntl] = *(const bf16x8*)((char*)pl2 + byte);
            }
            #pragma unroll
            for (int m = 0; m < MT; ++m) {
                size_t base = ((size_t)(m * KC + kc) * TAPS + k) * 3;
                bf16x8 a0 = *(const bf16x8*)(wfrag + (base + 0) * 512 + lane * 8);
                bf16x8 a1 = *(const bf16x8*)(wfrag + (base + 1) * 512 + lane * 8);
                bf16x8 a2 = *(const bf16x8*)(wfrag + (base + 2) * 512 + lane * 8);
                #pragma unroll
                for (int ntl = 0; ntl < NTL; ++ntl) {
                    f32x4 a = acc[ntl][m];
                    a = __builtin_amdgcn_mfma_f32_16x16x32_bf16(a0, B0[ntl], a, 0, 0, 0);
                    a = __builtin_amdgcn_mfma_f32_16x16x32_bf16(a1, B0[ntl], a, 0, 0, 0);
                    a = __builtin_amdgcn_mfma_f32_16x16x32_bf16(a2, B0[ntl], a, 0, 0, 0);
                    a = __builtin_amdgcn_mfma_f32_16x16x32_bf16(a0, B1[ntl], a, 0, 0, 0);
                    a = __builtin_amdgcn_mfma_f32_16x16x32_bf16(a1, B1[ntl], a, 0, 0, 0);
                    a = __builtin_amdgcn_mfma_f32_16x16x32_bf16(a0, B2[ntl], a, 0, 0, 0);
                    acc[ntl][m] = a;
                }
            }
        }
    }

    #pragma unroll
    for (int ntl = 0; ntl < NTL; ++ntl) {
        int n = t0 + (wv * NTL + ntl) * 16 + ncol;
        if (n < Lout) {
            #pragma unroll
            for (int m = 0; m < MT; ++m) {
                int co0 = m * 16 + nq * 4;
                float4 bb = *(const float4*)(bias + co0);
                float4 vv;
                vv.x = elu(acc[ntl][m][0] + bb.x);
                vv.y = elu(acc[ntl][m][1] + bb.y);
                vv.z = elu(acc[ntl][m][2] + bb.z);
                vv.w = elu(acc[ntl][m][3] + bb.w);
                if constexpr (OUTMODE == 0) {
                    *(float4*)(Hout + ((size_t)b * Lout + n) * COUT + co0) = vv;
                } else if constexpr (OUTMODE == 1) {
                    *(float4*)(Hout + ((size_t)b * (Lout >> 1) + (n >> 1)) * (2 * COUT)
                               + (n & 1) * COUT + co0) = vv;
                } else {
                    Hout[((size_t)b * COUT + co0 + 0) * Lout + n] = vv.x;
                    Hout[((size_t)b * COUT + co0 + 1) * Lout + n] = vv.y;
                    Hout[((size_t)b * COUT + co0 + 2) * Lout + n] = vv.z;
                    Hout[((size_t)b * COUT + co0 + 3) * Lout + n] = vv.w;
                }
            }
        }
    }
}

// ---------------- VQ prep: cc (fp32, +||c||^2) + (-2c) hi/lo bf16 B-frags ---
__global__ __launch_bounds__(256) void vq_prep_kernel(
    const float* __restrict__ cbs, float* __restrict__ cc, short* __restrict__ cbf)
{
    int c = blockIdx.x * 256 + threadIdx.x;   // 0..2047
    if (c >= 2048) return;
    int cb = c >> 10, nl = c & 1023;
    const float* row = cbs + (size_t)c * 64;
    float v[64];
    float s = 0.f;
    #pragma unroll
    for (int i = 0; i < 16; ++i) {
        float4 q = ((const float4*)row)[i];
        v[4*i+0] = q.x; v[4*i+1] = q.y; v[4*i+2] = q.z; v[4*i+3] = q.w;
        s += q.x*q.x + q.y*q.y + q.z*q.z + q.w*q.w;
    }
    cc[c] = s;
    int nt = nl >> 4, nc = nl & 15;
    #pragma unroll
    for (int kc = 0; kc < 2; ++kc)
        #pragma unroll
        for (int lh = 0; lh < 4; ++lh) {
            bf16x8 ph, pl;
            #pragma unroll
            for (int j = 0; j < 8; ++j) {
                float f = -2.0f * v[kc*32 + lh*8 + j];   // exact scaling
                short h = f2bf(f);
                ph[j] = h;
                pl[j] = f2bf(f - bf2f(h));
            }
            size_t base = ((((size_t)cb*64 + nt)*2 + kc)*2);
            *(bf16x8*)(cbf + ((base + 0)*64 + (lh*16 + nc)) * 8) = ph;
            *(bf16x8*)(cbf + ((base + 1)*64 + (lh*16 + nc)) * 8) = pl;
        }
}

__global__ void zero_cnt_kernel(int* cnt) {
    if (threadIdx.x == 0 && blockIdx.x == 0) { cnt[0] = 0; cnt[1] = 0; }
}

// ---------------- VQ main: MFMA scores, double-buffered 64-code chunks ------
#define VQ_MARGIN 0.04f

__global__ __launch_bounds__(256)
__attribute__((amdgpu_waves_per_eu(4, 4)))
void vq_mfma_kernel(
    const float* __restrict__ z, const short* __restrict__ cbf,
    const float* __restrict__ ccg, int* __restrict__ out,
    int* __restrict__ cnt, int* __restrict__ list0, int* __restrict__ list1)
{
    __shared__ __align__(16) short sbuf[16384];
    short* zf0 = sbuf;            // [8 mt][2 kc][64 lane][8] hi (16 KB)
    short* zf1 = sbuf + 8192;     // lo (16 KB)

    const int T = 2000;
    int mblk = blockIdx.x;
    int cb   = blockIdx.y;
    int b    = blockIdx.z;
    int t0   = mblk * 128;
    int tid  = threadIdx.x;
    int lane = tid & 63;
    int wv   = tid >> 6;
    int* list = cb ? list1 : list0;

    const float* zb = z + ((size_t)b*128 + (size_t)cb*64) * T;
    for (int e = tid; e < 128 * 8; e += 256) {
        int tl = e & 127;
        int d0 = (e >> 7) * 8;
        int tt = t0 + tl; if (tt > T - 1) tt = T - 1;
        bf16x8 hi, lo;
        #pragma unroll
        for (int jj = 0; jj < 8; ++jj) {
            float v = zb[(size_t)(d0 + jj) * T + tt];
            short h = f2bf(v);
            hi[jj] = h;
            lo[jj] = f2bf(v - bf2f(h));
        }
        int mt = tl >> 4, kc = d0 >> 5;
        int lw = ((d0 & 31) >> 3) * 16 + (tl & 15);
        int idx = ((mt*2 + kc)*64 + lw) * 8;
        *(bf16x8*)&zf0[idx] = hi;
        *(bf16x8*)&zf1[idx] = lo;
    }
    __syncthreads();

    bf16x8 ah[2][2], al[2][2];
    #pragma unroll
    for (int mtl = 0; mtl < 2; ++mtl)
        #pragma unroll
        for (int kc = 0; kc < 2; ++kc) {
            int idx = ((((wv*2+mtl)*2 + kc)*64) + lane)*8;
            ah[mtl][kc] = *(const bf16x8*)&zf0[idx];
            al[mtl][kc] = *(const bf16x8*)&zf1[idx];
        }
    __syncthreads();   // zf reads complete; sbuf is now the chunk double-buffer

    float best[2][4], second[2][4]; int bidx[2][4];
    #pragma unroll
    for (int m = 0; m < 2; ++m)
        #pragma unroll
        for (int j = 0; j < 4; ++j) { best[m][j] = 3.4e38f; second[m][j] = 3.4e38f; bidx[m][j] = 0; }

    const short* cbase = cbf + (size_t)cb * (64*2*2*64*8);
    const float* ccb   = ccg + cb * 1024;
    int c15 = lane & 15;

    {   // synchronous copy of chunk 0 into buf 0
        const float4* src = (const float4*)cbase;
        float4* dst = (float4*)sbuf;
        #pragma unroll
        for (int i = 0; i < 4; ++i) dst[tid + 256*i] = src[tid + 256*i];
    }
    __syncthreads();

    for (int ch = 0; ch < 16; ++ch) {
        short* cur = sbuf + (ch & 1) * 8192;
        short* nxt = sbuf + ((ch + 1) & 1) * 8192;
        float4 pre0, pre1, pre2, pre3;
        if (ch < 15) {
            const float4* src = (const float4*)(cbase + (size_t)(ch + 1) * 8192);
            pre0 = src[tid];       pre1 = src[tid + 256];
            pre2 = src[tid + 512]; pre3 = src[tid + 768];
        }

        #pragma unroll
        for (int ntl = 0; ntl < 4; ++ntl) {
            bf16x8 b0h = *(const bf16x8*)&cur[(((ntl*2 + 0)*2 + 0)*64 + lane)*8];
            bf16x8 b0l = *(const bf16x8*)&cur[(((ntl*2 + 0)*2 + 1)*64 + lane)*8];
            bf16x8 b1h = *(const bf16x8*)&cur[(((ntl*2 + 1)*2 + 0)*64 + lane)*8];
            bf16x8 b1l = *(const bf16x8*)&cur[(((ntl*2 + 1)*2 + 1)*64 + lane)*8];
            int  code = ch*64 + ntl*16 + c15;
            float ccv = ccb[code];
            #pragma unroll
            for (int mtl = 0; mtl < 2; ++mtl) {
                f32x4 p = {ccv, ccv, ccv, ccv};
                __builtin_amdgcn_s_setprio(1);
                p = __builtin_amdgcn_mfma_f32_16x16x32_bf16(ah[mtl][0], b0h, p, 0, 0, 0);
                p = __builtin_amdgcn_mfma_f32_16x16x32_bf16(al[mtl][0], b0h, p, 0, 0, 0);
                p = __builtin_amdgcn_mfma_f32_16x16x32_bf16(ah[mtl][0], b0l, p, 0, 0, 0);
                p = __builtin_amdgcn_mfma_f32_16x16x32_bf16(ah[mtl][1], b1h, p, 0, 0, 0);
                p = __builtin_amdgcn_mfma_f32_16x16x32_bf16(al[mtl][1], b1h, p, 0, 0, 0);
                p = __builtin_amdgcn_mfma_f32_16x16x32_bf16(ah[mtl][1], b1l, p, 0, 0, 0);
                __builtin_amdgcn_s_setprio(0);
                #pragma unroll
                for (int j = 0; j < 4; ++j) {
                    float s = p[j];
                    bool lt = s < best[mtl][j];
                    second[mtl][j] = __builtin_amdgcn_fmed3f(best[mtl][j], s, second[mtl][j]);
                    best[mtl][j]   = fminf(best[mtl][j], s);
                    bidx[mtl][j]   = lt ? code : bidx[mtl][j];
                }
            }
        }

        if (ch < 15) {
            float4* dst = (float4*)nxt;
            dst[tid]       = pre0;  dst[tid + 256] = pre1;
            dst[tid + 512] = pre2;  dst[tid + 768] = pre3;
        }
        __syncthreads();
    }

    #pragma unroll
    for (int m = 0; m < 2; ++m)
        #pragma unroll
        for (int j = 0; j < 4; ++j) {
            float bv = best[m][j], sv = second[m][j]; int bi = bidx[m][j];
            #pragma unroll
            for (int d = 1; d < 16; d <<= 1) {
                float ob = __shfl_xor(bv, d, 64);
                float os = __shfl_xor(sv, d, 64);
                int   oi = __shfl_xor(bi, d, 64);
                float loser = fmaxf(bv, ob);
                sv = fminf(fminf(sv, os), loser);
                bool sw = ob < bv;
                bv = fminf(bv, ob);
                bi = sw ? oi : bi;
            }
            if ((lane & 15) == 0) {
                int t = t0 + (wv*2 + m)*16 + (lane >> 4)*4 + j;
                if (t < T) {
                    out[((size_t)cb*64 + b)*T + t] = bi;
                    if (sv - bv < VQ_MARGIN) {
                        int pos = atomicAdd(&cnt[cb], 1);
                        list[pos] = (b << 11) | t;
                    }
                }
            }
        }
}

// ---------------- VQ rescore: 4 same-cb flags/iter share cb+w streams -------
__global__ __launch_bounds__(256) void vq_rescore_kernel(
    const float* __restrict__ H3, const float* __restrict__ wq,
    const float* __restrict__ bq, const float* __restrict__ cbs,
    const float* __restrict__ ccg, const int* __restrict__ cnt,
    const int* __restrict__ list0, const int* __restrict__ list1,
    int* __restrict__ out)
{
    const int T = 2000;
    __shared__ float hp[4][4][448];
    __shared__ float zsh[4][4][64];
    int tid = threadIdx.x, lane = tid & 63, wv = tid >> 6;
    int cb = blockIdx.y;
    const int* list = cb ? list1 : list0;
    int count = cnt[cb];
    int gw = blockIdx.x * 4 + wv, nw = gridDim.x * 4;

    const float* cbase = cbs + (size_t)cb * 1024 * 64;
    const float* ccb   = ccg + cb * 1024;
    int d = cb * 64 + lane;
    const float4* wp = (const float4*)(wq + (size_t)d * 448);
    float bqd = bq[d];

    for (int i0 = gw * 4; i0 < count; i0 += nw * 4) {
        int bf_[4], tf_[4];
        #pragma unroll
        for (int f = 0; f < 4; ++f) {
            int idx = i0 + f; if (idx > count - 1) idx = count - 1;
            int e = list[idx];
            bf_[f] = e >> 11; tf_[f] = e & 2047;
        }

        #pragma unroll
        for (int f = 0; f < 4; ++f) {
            size_t base = (size_t)bf_[f] * T * 64;
            #pragma unroll
            for (int kk = 0; kk < 7; ++kk) {
                int a = tf_[f] - 6 + kk;
                hp[wv][f][lane * 7 + kk] = (a >= 0) ? H3[base + (size_t)a * 64 + lane] : 0.0f;
            }
        }

        float pa[4][4];
        #pragma unroll
        for (int f = 0; f < 4; ++f)
            #pragma unroll
            for (int j = 0; j < 4; ++j) pa[f][j] = 0.f;
        #pragma unroll 4
        for (int q = 0; q < 112; ++q) {
            float4 w4 = wp[q];
            #pragma unroll
            for (int f = 0; f < 4; ++f) {
                float4 h = *(const float4*)&hp[wv][f][4 * q];
                pa[f][0] = fmaf(w4.x, h.x, pa[f][0]);
                pa[f][1] = fmaf(w4.y, h.y, pa[f][1]);
                pa[f][2] = fmaf(w4.z, h.z, pa[f][2]);
                pa[f][3] = fmaf(w4.w, h.w, pa[f][3]);
            }
        }
        #pragma unroll
        for (int f = 0; f < 4; ++f) {
            float zv = (pa[f][0] + pa[f][1]) + (pa[f][2] + pa[f][3]) + bqd;
            zsh[wv][f][lane] = zv > 0.f ? zv : expm1f(zv);
        }

        float bv[4]; int bi[4];
        #pragma unroll
        for (int f = 0; f < 4; ++f) { bv[f] = 3.4e38f; bi[f] = 0; }
        for (int ii = 0; ii < 16; ++ii) {
            int code = ii * 64 + lane;
            const float4* cp = (const float4*)(cbase + (size_t)code * 64);
            float dd[4][4];
            #pragma unroll
            for (int f = 0; f < 4; ++f)
                #pragma unroll
                for (int j = 0; j < 4; ++j) dd[f][j] = 0.f;
            #pragma unroll
            for (int q = 0; q < 16; ++q) {
                float4 cv = cp[q];
                #pragma unroll
                for (int f = 0; f < 4; ++f) {
                    float4 za = *(const float4*)&zsh[wv][f][4 * q];
                    dd[f][0] = fmaf(za.x, cv.x, dd[f][0]);
                    dd[f][1] = fmaf(za.y, cv.y, dd[f][1]);
                    dd[f][2] = fmaf(za.z, cv.z, dd[f][2]);
                    dd[f][3] = fmaf(za.w, cv.w, dd[f][3]);
                }
            }
            float cc0 = ccb[code];
            #pragma unroll
            for (int f = 0; f < 4; ++f) {
                float s = fmaf(-2.0f, (dd[f][0] + dd[f][1]) + (dd[f][2] + dd[f][3]), cc0);
                if (s < bv[f]) { bv[f] = s; bi[f] = code; }
            }
        }
        #pragma unroll
        for (int ddp = 1; ddp < 64; ddp <<= 1) {
            #pragma unroll
            for (int f = 0; f < 4; ++f) {
                float ov = __shfl_xor(bv[f], ddp, 64);
                int   oi = __shfl_xor(bi[f], ddp, 64);
                if (ov < bv[f] || (ov == bv[f] && oi < bi[f])) { bv[f] = ov; bi[f] = oi; }
            }
        }
        if (lane == 0) {
            #pragma unroll
            for (int f = 0; f < 4; ++f)
                out[((size_t)cb * 64 + bf_[f]) * T + tf_[f]] = bi[f];
        }
    }
}

extern "C" void kernel_launch(void* const* d_in, const int* in_sizes, int n_in,
                              void* d_out, int out_size, void* d_ws, size_t ws_size,
                              hipStream_t stream)
{
    const float* x   = (const float*)d_in[0];
    const float* w0  = (const float*)d_in[1];
    const float* b0  = (const float*)d_in[2];
    const float* w1  = (const float*)d_in[3];
    const float* b1  = (const float*)d_in[4];
    const float* w2  = (const float*)d_in[5];
    const float* b2  = (const float*)d_in[6];
    const float* w3  = (const float*)d_in[7];
    const float* b3  = (const float*)d_in[8];
    const float* wq  = (const float*)d_in[9];
    const float* bq  = (const float*)d_in[10];
    const float* cbs = (const float*)d_in[11];
    int* out = (int*)d_out;

    // two 98,304,000-byte regions (proven footprint)
    char* r1 = (char*)d_ws;
    char* r2 = r1 + 98304000;
    float* H1 = (float*)r2;               // [64][6000][64]  (phase-split)
    float* H2 = (float*)r1;               // [64][6000][64]
    float* H3 = (float*)r2;               // [64][2000][64]  (over dead H1)
    float* z  = (float*)(r2 + 32768000);  // [64][128][2000] fp32

    // weight fragments in d_out (dead until vq_mfma rewrites it)
    short* wf1 = (short*)d_out;           // 12288 shorts
    short* wf2 = wf1 + 12288;             // 49152
    short* wf3 = wf1 + 61440;             // 86016
    short* wf4 = wf1 + 147456;            // 172032 -> ends at 319488 shorts

    // VQ prep data in r1 (free after conv3 consumes H2)
    short* cbf   = (short*)r1;
    float* cc    = (float*)(r1 + 524288);
    int*   cnt   = (int*)(r1 + 540000);
    int*   list0 = (int*)(r1 + 1000000);
    int*   list1 = (int*)(r1 + 2100000);

    // weight prep (reads inputs only)
    wprep3_ps_kernel<16, 32><<<1, 32, 0, stream>>>(w1, wf1);
    wprep3_ps_kernel<32, 64><<<1, 64, 0, stream>>>(w2, wf2);
    wprep3_kernel<64, 64, 7><<<1, 64, 0, stream>>>(w3, wf3);
    wprep3_kernel<64, 128, 7><<<1, 128, 0, stream>>>(wq, wf4);

    // fused conv0+conv1: x -> H1 (phase-split), H0 recomputed in-kernel
    conv01_kernel<<<dim3(94, 64), 256, 0, stream>>>(x, w0, b0, wf1, b1, H1);
    // conv2: H1 -> H2, stride-1 K=4 over 64ch, NT=64 tiles (4-5 blocks/CU)
    conv_mfma3_kernel<1, 64, 64, 1, 4, 3, 0, 1><<<dim3(94, 64), 256, 0, stream>>>(
        H1, wf2, b2, H2, 6000, 6000);
    // conv3: H2 -> H3, stride 3, K=7, t-major out
    conv_mfma3_kernel<3, 64, 64, 1, 7, 6, 0, 1><<<dim3(32, 64), 256, 0, stream>>>(
        H2, wf3, b3, H3, 6000, 2000);

    // VQ prep into r1 (H2 now dead)
    vq_prep_kernel<<<8, 256, 0, stream>>>(cbs, cc, cbf);
    zero_cnt_kernel<<<1, 64, 0, stream>>>(cnt);

    // conv4: H3 -> z (fp32 [co][t]), stride 1, K=7, NT=64 tiles
    conv_mfma3_kernel<1, 64, 128, 1, 7, 6, 2, 1><<<dim3(32, 64), 256, 0, stream>>>(
        H3, wf4, bq, z, 2000, 2000);

    // VQ: MFMA scores + per-cb flag lists, then 4-way shared exact rescore
    vq_mfma_kernel<<<dim3(16, 2, 64), 256, 0, stream>>>(z, cbf, cc, out, cnt, list0, list1);
    vq_rescore_kernel<<<dim3(512, 2), 256, 0, stream>>>(H3, wq, bq, cbs, cc, cnt, list0, list1, out);
}

// Round 23
// 637.080 us; speedup vs baseline: 1.0608x; 1.0608x over previous
//
#include <hip/hip_runtime.h>
#include <hip/hip_bf16.h>
#include <cstddef>

// ---------------------------------------------------------------------------
// EncoderModule: 5x causal conv1d (K=7) + ELU, then 2x VQ argmin (1024 codes, D=64)
// B=64, L=48000, strides 2,2,2,3,1; channels 1->16->32->64->64->128
// Output: int32 indices, shape (2, 64, 2000)
//
// r23 = revert to the verified r21 configuration (637us, absmax 0).
// conv0 fused into conv1 (bit-identical H0 recompute). convs 2-4: 6-term
// split3-bf16 MFMA, fp32 t-major I/O, NTL=2 tiles for conv2/conv4 (r22's
// NT=64 halving regressed: +22us on conv2 — tile overhead beat occupancy).
// VQ: -2c codebook, ||c||^2 in accumulator init, med3 best/second, 2x16KB
// double-buffered chunks, waves_per_eu(4,4). gap<0.04 -> flag; 4-way rescore.
// ---------------------------------------------------------------------------

using bf16x8 = __attribute__((ext_vector_type(8))) short;
using s16x4  = __attribute__((ext_vector_type(4))) short;
using f32x4  = __attribute__((ext_vector_type(4))) float;

static __device__ __forceinline__ short f2bf(float f) {
    __hip_bfloat16 h = __float2bfloat16(f);   // RNE
    union { __hip_bfloat16 h; short s; } u; u.h = h;
    return u.s;
}
static __device__ __forceinline__ float bf2f(short s) {
    union { unsigned u; float f; } v;
    v.u = ((unsigned)(unsigned short)s) << 16;
    return v.f;
}
static __device__ __forceinline__ void split3(float v, short& s0, short& s1, short& s2) {
    s0 = f2bf(v);  float r1 = v  - bf2f(s0);   // exact
    s1 = f2bf(r1); float r2 = r1 - bf2f(s1);   // exact
    s2 = f2bf(r2);                             // residual ~2^-24 |v|
}
static __device__ __forceinline__ float elu(float v) {
    return v > 0.0f ? v : expm1f(v);
}

// ---------------- fused conv0+conv1 -----------------------------------------
__global__ __launch_bounds__(256) void conv01_kernel(
    const float* __restrict__ x, const float* __restrict__ w0,
    const float* __restrict__ b0, const short* __restrict__ wfrag,
    const float* __restrict__ bias, float* __restrict__ Hout)
{
    constexpr int CIN = 32, COUT = 32, NTL = 2, TAPS = 4, S = 1;
    constexpr int KC = 1, MT = 2, NT = 128, ROWS = 131, ROWB = 64;
    constexpr int Lin = 12000, Lout = 12000;
    __shared__ __align__(16) short pl0[ROWS * CIN];
    __shared__ __align__(16) short pl1[ROWS * CIN];
    __shared__ __align__(16) short pl2[ROWS * CIN];
    __shared__ float xs[536];

    int nb = blockIdx.x, b = blockIdx.y;
    int t0 = nb * NT;
    int tid = threadIdx.x, lane = tid & 63, wv = tid >> 6;
    int g0 = t0 - 3;                      // first H0 row (u) in the tile

    const float* xb = x + (size_t)b * 48000;
    int xbase = 4 * g0 - 6;
    for (int i = tid; i < 529; i += 256) {
        int g = xbase + i;
        xs[i] = (g >= 0 && g < 48000) ? xb[g] : 0.0f;
    }
    __syncthreads();

    for (int e = tid; e < ROWS * 8; e += 256) {
        int rr = e >> 3, sl = e & 7;
        int g = g0 + rr;
        int ph = sl >> 2;
        int xr = (rr >> 1) & 3;           // CIN==32 swizzle
        int byte = rr * ROWB + ((((sl >> 1) ^ xr) << 4) | ((sl & 1) << 3));
        bool ok = (g >= 0 && g < Lin);
        int bx = 4 * rr + 2 * ph;
        s16x4 q0, q1, q2;
        #pragma unroll
        for (int j = 0; j < 4; ++j) {
            float v = 0.0f;
            if (ok) {
                int co = (sl & 3) * 4 + j;
                const float* wp = w0 + co * 7;
                float acc = 0.f;
                #pragma unroll
                for (int k = 0; k < 7; ++k)
                    acc = fmaf(wp[k], xs[bx + k], acc);
                v = elu(acc + b0[co]);
            }
            short a0, a1, a2;
            split3(v, a0, a1, a2);
            q0[j] = a0; q1[j] = a1; q2[j] = a2;
        }
        *(s16x4*)((char*)pl0 + byte) = q0;
        *(s16x4*)((char*)pl1 + byte) = q1;
        *(s16x4*)((char*)pl2 + byte) = q2;
    }
    __syncthreads();

    f32x4 acc[NTL][MT];
    #pragma unroll
    for (int n = 0; n < NTL; ++n)
        #pragma unroll
        for (int m = 0; m < MT; ++m) acc[n][m] = (f32x4){0.f, 0.f, 0.f, 0.f};

    int ncol = lane & 15, nq = lane >> 4;

    for (int k = 0; k < TAPS; ++k) {
        #pragma unroll
        for (int kc = 0; kc < KC; ++kc) {
            int colb = (kc * 32 + nq * 8) * 2;
            bf16x8 B0[NTL], B1[NTL], B2[NTL];
            #pragma unroll
            for (int ntl = 0; ntl < NTL; ++ntl) {
                int r  = S * ((wv * NTL + ntl) * 16 + ncol) + k;
                int xr = (r >> 1) & 3;
                int byte = r * ROWB + (colb ^ (xr << 4));
                B0[ntl] = *(const bf16x8*)((char*)pl0 + byte);
                B1[ntl] = *(const bf16x8*)((char*)pl1 + byte);
                B2[ntl] = *(const bf16x8*)((char*)pl2 + byte);
            }
            #pragma unroll
            for (int m = 0; m < MT; ++m) {
                size_t base = ((size_t)(m * KC + kc) * TAPS + k) * 3;
                bf16x8 a0 = *(const bf16x8*)(wfrag + (base + 0) * 512 + lane * 8);
                bf16x8 a1 = *(const bf16x8*)(wfrag + (base + 1) * 512 + lane * 8);
                bf16x8 a2 = *(const bf16x8*)(wfrag + (base + 2) * 512 + lane * 8);
                #pragma unroll
                for (int ntl = 0; ntl < NTL; ++ntl) {
                    f32x4 a = acc[ntl][m];
                    a = __builtin_amdgcn_mfma_f32_16x16x32_bf16(a0, B0[ntl], a, 0, 0, 0);
                    a = __builtin_amdgcn_mfma_f32_16x16x32_bf16(a1, B0[ntl], a, 0, 0, 0);
                    a = __builtin_amdgcn_mfma_f32_16x16x32_bf16(a2, B0[ntl], a, 0, 0, 0);
                    a = __builtin_amdgcn_mfma_f32_16x16x32_bf16(a0, B1[ntl], a, 0, 0, 0);
                    a = __builtin_amdgcn_mfma_f32_16x16x32_bf16(a1, B1[ntl], a, 0, 0, 0);
                    a = __builtin_amdgcn_mfma_f32_16x16x32_bf16(a0, B2[ntl], a, 0, 0, 0);
                    acc[ntl][m] = a;
                }
            }
        }
    }

    #pragma unroll
    for (int ntl = 0; ntl < NTL; ++ntl) {
        int n = t0 + (wv * NTL + ntl) * 16 + ncol;
        if (n < Lout) {
            #pragma unroll
            for (int m = 0; m < MT; ++m) {
                int co0 = m * 16 + nq * 4;
                float4 bb = *(const float4*)(bias + co0);
                float4 vv;
                vv.x = elu(acc[ntl][m][0] + bb.x);
                vv.y = elu(acc[ntl][m][1] + bb.y);
                vv.z = elu(acc[ntl][m][2] + bb.z);
                vv.w = elu(acc[ntl][m][3] + bb.w);
                *(float4*)(Hout + ((size_t)b * (Lout >> 1) + (n >> 1)) * (2 * COUT)
                           + (n & 1) * COUT + co0) = vv;
            }
        }
    }
}

// ---------------- weight prep: 3-level bf16 A-fragments ---------------------
template<int CIN, int COUT, int TAPS>
__global__ void wprep3_kernel(const float* __restrict__ w, short* __restrict__ frag)
{
    constexpr int KC = CIN / 32;
    int co = threadIdx.x;
    if (co >= COUT) return;
    int mt = co >> 4, nc = co & 15;
    for (int kc = 0; kc < KC; ++kc)
        for (int k = 0; k < TAPS; ++k)
            #pragma unroll
            for (int lh = 0; lh < 4; ++lh) {
                bf16x8 p0, p1, p2;
                #pragma unroll
                for (int j = 0; j < 8; ++j) {
                    int ci = kc * 32 + lh * 8 + j;
                    float f = w[(size_t)co * CIN * 7 + ci * 7 + k];
                    short a, bb, c; split3(f, a, bb, c);
                    p0[j] = a; p1[j] = bb; p2[j] = c;
                }
                size_t base = ((size_t)(mt * KC + kc) * TAPS + k) * 3;
                int off = (lh * 16 + nc) * 8;
                *(bf16x8*)(frag + (base + 0) * 512 + off) = p0;
                *(bf16x8*)(frag + (base + 1) * 512 + off) = p1;
                *(bf16x8*)(frag + (base + 2) * 512 + off) = p2;
            }
}

// phase-split packing (stride-2 K=7 -> stride-1 K=4 over doubled channels)
template<int CINH, int COUT>
__global__ void wprep3_ps_kernel(const float* __restrict__ w, short* __restrict__ frag)
{
    constexpr int CIN = 2 * CINH;
    constexpr int KC  = CIN / 32;
    int co = threadIdx.x;
    if (co >= COUT) return;
    int mt = co >> 4, nc = co & 15;
    for (int kc = 0; kc < KC; ++kc)
        for (int m = 0; m < 4; ++m)
            #pragma unroll
            for (int lh = 0; lh < 4; ++lh) {
                bf16x8 p0, p1, p2;
                #pragma unroll
                for (int j = 0; j < 8; ++j) {
                    int cp = kc * 32 + lh * 8 + j;
                    float f;
                    if (cp < CINH)  f = w[(size_t)co * CINH * 7 + cp * 7 + 2 * m];
                    else if (m < 3) f = w[(size_t)co * CINH * 7 + (cp - CINH) * 7 + 2 * m + 1];
                    else            f = 0.0f;
                    short a, bb, c; split3(f, a, bb, c);
                    p0[j] = a; p1[j] = bb; p2[j] = c;
                }
                size_t base = ((size_t)(mt * KC + kc) * 4 + m) * 3;
                int off = (lh * 16 + nc) * 8;
                *(bf16x8*)(frag + (base + 0) * 512 + off) = p0;
                *(bf16x8*)(frag + (base + 1) * 512 + off) = p1;
                *(bf16x8*)(frag + (base + 2) * 512 + off) = p2;
            }
}

// ---------------- conv via 6-term split3-bf16 MFMA, t-major fp32 I/O --------
template<int S, int CIN, int COUT, int NTL, int TAPS, int PAD, int OUTMODE>
__global__ __launch_bounds__(256) void conv_mfma3_kernel(
    const float* __restrict__ Hin, const short* __restrict__ wfrag,
    const float* __restrict__ bias, float* __restrict__ Hout,
    int Lin, int Lout)
{
    constexpr int KC   = CIN / 32;
    constexpr int MT   = COUT / 16;
    constexpr int NT   = NTL * 64;
    constexpr int ROWS = (NT - 1) * S + TAPS;
    constexpr int ROWB = CIN * 2;
    constexpr int NSL  = CIN / 4;
    __shared__ __align__(16) short pl0[ROWS * CIN];
    __shared__ __align__(16) short pl1[ROWS * CIN];
    __shared__ __align__(16) short pl2[ROWS * CIN];

    int nb = blockIdx.x, b = blockIdx.y;
    int t0 = nb * NT;
    int tid = threadIdx.x, lane = tid & 63, wv = tid >> 6;
    int g0 = t0 * S - PAD;

    const float* inb = Hin + (size_t)b * Lin * CIN;
    for (int e = tid; e < ROWS * NSL; e += 256) {
        int rr = e / NSL, sl = e % NSL;
        int g = g0 + rr;
        float4 v = {0.f, 0.f, 0.f, 0.f};
        if (g >= 0 && g < Lin)
            v = *(const float4*)(inb + (size_t)g * CIN + sl * 4);
        int xr = (CIN == 64) ? (rr & 7) : ((rr >> 1) & 3);
        int byte = rr * ROWB + ((((sl >> 1) ^ xr) << 4) | ((sl & 1) << 3));
        s16x4 q0, q1, q2;
        short a0, a1, a2;
        split3(v.x, a0, a1, a2); q0[0] = a0; q1[0] = a1; q2[0] = a2;
        split3(v.y, a0, a1, a2); q0[1] = a0; q1[1] = a1; q2[1] = a2;
        split3(v.z, a0, a1, a2); q0[2] = a0; q1[2] = a1; q2[2] = a2;
        split3(v.w, a0, a1, a2); q0[3] = a0; q1[3] = a1; q2[3] = a2;
        *(s16x4*)((char*)pl0 + byte) = q0;
        *(s16x4*)((char*)pl1 + byte) = q1;
        *(s16x4*)((char*)pl2 + byte) = q2;
    }
    __syncthreads();

    f32x4 acc[NTL][MT];
    #pragma unroll
    for (int n = 0; n < NTL; ++n)
        #pragma unroll
        for (int m = 0; m < MT; ++m) acc[n][m] = (f32x4){0.f, 0.f, 0.f, 0.f};

    int ncol = lane & 15, nq = lane >> 4;

    for (int k = 0; k < TAPS; ++k) {
        #pragma unroll
        for (int kc = 0; kc < KC; ++kc) {
            int colb = (kc * 32 + nq * 8) * 2;
            bf16x8 B0[NTL], B1[NTL], B2[NTL];
            #pragma unroll
            for (int ntl = 0; ntl < NTL; ++ntl) {
                int r  = S * ((wv * NTL + ntl) * 16 + ncol) + k;
                int xr = (CIN == 64) ? (r & 7) : ((r >> 1) & 3);
                int byte = r * ROWB + (colb ^ (xr << 4));
                B0[ntl] = *(const bf16x8*)((char*)pl0 + byte);
                B1[ntl] = *(const bf16x8*)((char*)pl1 + byte);
                B2[ntl] = *(const bf16x8*)((char*)pl2 + byte);
            }
            #pragma unroll
            for (int m = 0; m < MT; ++m) {
                size_t base = ((size_t)(m * KC + kc) * TAPS + k) * 3;
                bf16x8 a0 = *(const bf16x8*)(wfrag + (base + 0) * 512 + lane * 8);
                bf16x8 a1 = *(const bf16x8*)(wfrag + (base + 1) * 512 + lane * 8);
                bf16x8 a2 = *(const bf16x8*)(wfrag + (base + 2) * 512 + lane * 8);
                #pragma unroll
                for (int ntl = 0; ntl < NTL; ++ntl) {
                    f32x4 a = acc[ntl][m];
                    a = __builtin_amdgcn_mfma_f32_16x16x32_bf16(a0, B0[ntl], a, 0, 0, 0);
                    a = __builtin_amdgcn_mfma_f32_16x16x32_bf16(a1, B0[ntl], a, 0, 0, 0);
                    a = __builtin_amdgcn_mfma_f32_16x16x32_bf16(a2, B0[ntl], a, 0, 0, 0);
                    a = __builtin_amdgcn_mfma_f32_16x16x32_bf16(a0, B1[ntl], a, 0, 0, 0);
                    a = __builtin_amdgcn_mfma_f32_16x16x32_bf16(a1, B1[ntl], a, 0, 0, 0);
                    a = __builtin_amdgcn_mfma_f32_16x16x32_bf16(a0, B2[ntl], a, 0, 0, 0);
                    acc[ntl][m] = a;
                }
            }
        }
    }

    #pragma unroll
    for (int ntl = 0; ntl < NTL; ++ntl) {
        int n = t0 + (wv * NTL + ntl) * 16 + ncol;
        if (n < Lout) {
            #pragma unroll
            for (int m = 0; m < MT; ++m) {
                int co0 = m * 16 + nq * 4;
                float4 bb = *(const float4*)(bias + co0);
                float4 vv;
                vv.x = elu(acc[ntl][m][0] + bb.x);
                vv.y = elu(acc[ntl][m][1] + bb.y);
                vv.z = elu(acc[ntl][m][2] + bb.z);
                vv.w = elu(acc[ntl][m][3] + bb.w);
                if constexpr (OUTMODE == 0) {
                    *(float4*)(Hout + ((size_t)b * Lout + n) * COUT + co0) = vv;
                } else if constexpr (OUTMODE == 1) {
                    *(float4*)(Hout + ((size_t)b * (Lout >> 1) + (n >> 1)) * (2 * COUT)
                               + (n & 1) * COUT + co0) = vv;
                } else {
                    Hout[((size_t)b * COUT + co0 + 0) * Lout + n] = vv.x;
                    Hout[((size_t)b * COUT + co0 + 1) * Lout + n] = vv.y;
                    Hout[((size_t)b * COUT + co0 + 2) * Lout + n] = vv.z;
                    Hout[((size_t)b * COUT + co0 + 3) * Lout + n] = vv.w;
                }
            }
        }
    }
}

// ---------------- VQ prep: cc (fp32, +||c||^2) + (-2c) hi/lo bf16 B-frags ---
__global__ __launch_bounds__(256) void vq_prep_kernel(
    const float* __restrict__ cbs, float* __restrict__ cc, short* __restrict__ cbf)
{
    int c = blockIdx.x * 256 + threadIdx.x;   // 0..2047
    if (c >= 2048) return;
    int cb = c >> 10, nl = c & 1023;
    const float* row = cbs + (size_t)c * 64;
    float v[64];
    float s = 0.f;
    #pragma unroll
    for (int i = 0; i < 16; ++i) {
        float4 q = ((const float4*)row)[i];
        v[4*i+0] = q.x; v[4*i+1] = q.y; v[4*i+2] = q.z; v[4*i+3] = q.w;
        s += q.x*q.x + q.y*q.y + q.z*q.z + q.w*q.w;
    }
    cc[c] = s;
    int nt = nl >> 4, nc = nl & 15;
    #pragma unroll
    for (int kc = 0; kc < 2; ++kc)
        #pragma unroll
        for (int lh = 0; lh < 4; ++lh) {
            bf16x8 ph, pl;
            #pragma unroll
            for (int j = 0; j < 8; ++j) {
                float f = -2.0f * v[kc*32 + lh*8 + j];   // exact scaling
                short h = f2bf(f);
                ph[j] = h;
                pl[j] = f2bf(f - bf2f(h));
            }
            size_t base = ((((size_t)cb*64 + nt)*2 + kc)*2);
            *(bf16x8*)(cbf + ((base + 0)*64 + (lh*16 + nc)) * 8) = ph;
            *(bf16x8*)(cbf + ((base + 1)*64 + (lh*16 + nc)) * 8) = pl;
        }
}

__global__ void zero_cnt_kernel(int* cnt) {
    if (threadIdx.x == 0 && blockIdx.x == 0) { cnt[0] = 0; cnt[1] = 0; }
}

// ---------------- VQ main: MFMA scores, double-buffered 64-code chunks ------
#define VQ_MARGIN 0.04f

__global__ __launch_bounds__(256)
__attribute__((amdgpu_waves_per_eu(4, 4)))
void vq_mfma_kernel(
    const float* __restrict__ z, const short* __restrict__ cbf,
    const float* __restrict__ ccg, int* __restrict__ out,
    int* __restrict__ cnt, int* __restrict__ list0, int* __restrict__ list1)
{
    __shared__ __align__(16) short sbuf[16384];
    short* zf0 = sbuf;            // [8 mt][2 kc][64 lane][8] hi (16 KB)
    short* zf1 = sbuf + 8192;     // lo (16 KB)

    const int T = 2000;
    int mblk = blockIdx.x;
    int cb   = blockIdx.y;
    int b    = blockIdx.z;
    int t0   = mblk * 128;
    int tid  = threadIdx.x;
    int lane = tid & 63;
    int wv   = tid >> 6;
    int* list = cb ? list1 : list0;

    const float* zb = z + ((size_t)b*128 + (size_t)cb*64) * T;
    for (int e = tid; e < 128 * 8; e += 256) {
        int tl = e & 127;
        int d0 = (e >> 7) * 8;
        int tt = t0 + tl; if (tt > T - 1) tt = T - 1;
        bf16x8 hi, lo;
        #pragma unroll
        for (int jj = 0; jj < 8; ++jj) {
            float v = zb[(size_t)(d0 + jj) * T + tt];
            short h = f2bf(v);
            hi[jj] = h;
            lo[jj] = f2bf(v - bf2f(h));
        }
        int mt = tl >> 4, kc = d0 >> 5;
        int lw = ((d0 & 31) >> 3) * 16 + (tl & 15);
        int idx = ((mt*2 + kc)*64 + lw) * 8;
        *(bf16x8*)&zf0[idx] = hi;
        *(bf16x8*)&zf1[idx] = lo;
    }
    __syncthreads();

    bf16x8 ah[2][2], al[2][2];
    #pragma unroll
    for (int mtl = 0; mtl < 2; ++mtl)
        #pragma unroll
        for (int kc = 0; kc < 2; ++kc) {
            int idx = ((((wv*2+mtl)*2 + kc)*64) + lane)*8;
            ah[mtl][kc] = *(const bf16x8*)&zf0[idx];
            al[mtl][kc] = *(const bf16x8*)&zf1[idx];
        }
    __syncthreads();   // zf reads complete; sbuf is now the chunk double-buffer

    float best[2][4], second[2][4]; int bidx[2][4];
    #pragma unroll
    for (int m = 0; m < 2; ++m)
        #pragma unroll
        for (int j = 0; j < 4; ++j) { best[m][j] = 3.4e38f; second[m][j] = 3.4e38f; bidx[m][j] = 0; }

    const short* cbase = cbf + (size_t)cb * (64*2*2*64*8);
    const float* ccb   = ccg + cb * 1024;
    int c15 = lane & 15;

    {   // synchronous copy of chunk 0 into buf 0
        const float4* src = (const float4*)cbase;
        float4* dst = (float4*)sbuf;
        #pragma unroll
        for (int i = 0; i < 4; ++i) dst[tid + 256*i] = src[tid + 256*i];
    }
    __syncthreads();

    for (int ch = 0; ch < 16; ++ch) {
        short* cur = sbuf + (ch & 1) * 8192;
        short* nxt = sbuf + ((ch + 1) & 1) * 8192;
        float4 pre0, pre1, pre2, pre3;
        if (ch < 15) {
            const float4* src = (const float4*)(cbase + (size_t)(ch + 1) * 8192);
            pre0 = src[tid];       pre1 = src[tid + 256];
            pre2 = src[tid + 512]; pre3 = src[tid + 768];
        }

        #pragma unroll
        for (int ntl = 0; ntl < 4; ++ntl) {
            bf16x8 b0h = *(const bf16x8*)&cur[(((ntl*2 + 0)*2 + 0)*64 + lane)*8];
            bf16x8 b0l = *(const bf16x8*)&cur[(((ntl*2 + 0)*2 + 1)*64 + lane)*8];
            bf16x8 b1h = *(const bf16x8*)&cur[(((ntl*2 + 1)*2 + 0)*64 + lane)*8];
            bf16x8 b1l = *(const bf16x8*)&cur[(((ntl*2 + 1)*2 + 1)*64 + lane)*8];
            int  code = ch*64 + ntl*16 + c15;
            float ccv = ccb[code];
            #pragma unroll
            for (int mtl = 0; mtl < 2; ++mtl) {
                f32x4 p = {ccv, ccv, ccv, ccv};
                __builtin_amdgcn_s_setprio(1);
                p = __builtin_amdgcn_mfma_f32_16x16x32_bf16(ah[mtl][0], b0h, p, 0, 0, 0);
                p = __builtin_amdgcn_mfma_f32_16x16x32_bf16(al[mtl][0], b0h, p, 0, 0, 0);
                p = __builtin_amdgcn_mfma_f32_16x16x32_bf16(ah[mtl][0], b0l, p, 0, 0, 0);
                p = __builtin_amdgcn_mfma_f32_16x16x32_bf16(ah[mtl][1], b1h, p, 0, 0, 0);
                p = __builtin_amdgcn_mfma_f32_16x16x32_bf16(al[mtl][1], b1h, p, 0, 0, 0);
                p = __builtin_amdgcn_mfma_f32_16x16x32_bf16(ah[mtl][1], b1l, p, 0, 0, 0);
                __builtin_amdgcn_s_setprio(0);
                #pragma unroll
                for (int j = 0; j < 4; ++j) {
                    float s = p[j];
                    bool lt = s < best[mtl][j];
                    second[mtl][j] = __builtin_amdgcn_fmed3f(best[mtl][j], s, second[mtl][j]);
                    best[mtl][j]   = fminf(best[mtl][j], s);
                    bidx[mtl][j]   = lt ? code : bidx[mtl][j];
                }
            }
        }

        if (ch < 15) {
            float4* dst = (float4*)nxt;
            dst[tid]       = pre0;  dst[tid + 256] = pre1;
            dst[tid + 512] = pre2;  dst[tid + 768] = pre3;
        }
        __syncthreads();
    }

    #pragma unroll
    for (int m = 0; m < 2; ++m)
        #pragma unroll
        for (int j = 0; j < 4; ++j) {
            float bv = best[m][j], sv = second[m][j]; int bi = bidx[m][j];
            #pragma unroll
            for (int d = 1; d < 16; d <<= 1) {
                float ob = __shfl_xor(bv, d, 64);
                float os = __shfl_xor(sv, d, 64);
                int   oi = __shfl_xor(bi, d, 64);
                float loser = fmaxf(bv, ob);
                sv = fminf(fminf(sv, os), loser);
                bool sw = ob < bv;
                bv = fminf(bv, ob);
                bi = sw ? oi : bi;
            }
            if ((lane & 15) == 0) {
                int t = t0 + (wv*2 + m)*16 + (lane >> 4)*4 + j;
                if (t < T) {
                    out[((size_t)cb*64 + b)*T + t] = bi;
                    if (sv - bv < VQ_MARGIN) {
                        int pos = atomicAdd(&cnt[cb], 1);
                        list[pos] = (b << 11) | t;
                    }
                }
            }
        }
}

// ---------------- VQ rescore: 4 same-cb flags/iter share cb+w streams -------
__global__ __launch_bounds__(256) void vq_rescore_kernel(
    const float* __restrict__ H3, const float* __restrict__ wq,
    const float* __restrict__ bq, const float* __restrict__ cbs,
    const float* __restrict__ ccg, const int* __restrict__ cnt,
    const int* __restrict__ list0, const int* __restrict__ list1,
    int* __restrict__ out)
{
    const int T = 2000;
    __shared__ float hp[4][4][448];
    __shared__ float zsh[4][4][64];
    int tid = threadIdx.x, lane = tid & 63, wv = tid >> 6;
    int cb = blockIdx.y;
    const int* list = cb ? list1 : list0;
    int count = cnt[cb];
    int gw = blockIdx.x * 4 + wv, nw = gridDim.x * 4;

    const float* cbase = cbs + (size_t)cb * 1024 * 64;
    const float* ccb   = ccg + cb * 1024;
    int d = cb * 64 + lane;
    const float4* wp = (const float4*)(wq + (size_t)d * 448);
    float bqd = bq[d];

    for (int i0 = gw * 4; i0 < count; i0 += nw * 4) {
        int bf_[4], tf_[4];
        #pragma unroll
        for (int f = 0; f < 4; ++f) {
            int idx = i0 + f; if (idx > count - 1) idx = count - 1;
            int e = list[idx];
            bf_[f] = e >> 11; tf_[f] = e & 2047;
        }

        #pragma unroll
        for (int f = 0; f < 4; ++f) {
            size_t base = (size_t)bf_[f] * T * 64;
            #pragma unroll
            for (int kk = 0; kk < 7; ++kk) {
                int a = tf_[f] - 6 + kk;
                hp[wv][f][lane * 7 + kk] = (a >= 0) ? H3[base + (size_t)a * 64 + lane] : 0.0f;
            }
        }

        float pa[4][4];
        #pragma unroll
        for (int f = 0; f < 4; ++f)
            #pragma unroll
            for (int j = 0; j < 4; ++j) pa[f][j] = 0.f;
        #pragma unroll 4
        for (int q = 0; q < 112; ++q) {
            float4 w4 = wp[q];
            #pragma unroll
            for (int f = 0; f < 4; ++f) {
                float4 h = *(const float4*)&hp[wv][f][4 * q];
                pa[f][0] = fmaf(w4.x, h.x, pa[f][0]);
                pa[f][1] = fmaf(w4.y, h.y, pa[f][1]);
                pa[f][2] = fmaf(w4.z, h.z, pa[f][2]);
                pa[f][3] = fmaf(w4.w, h.w, pa[f][3]);
            }
        }
        #pragma unroll
        for (int f = 0; f < 4; ++f) {
            float zv = (pa[f][0] + pa[f][1]) + (pa[f][2] + pa[f][3]) + bqd;
            zsh[wv][f][lane] = zv > 0.f ? zv : expm1f(zv);
        }

        float bv[4]; int bi[4];
        #pragma unroll
        for (int f = 0; f < 4; ++f) { bv[f] = 3.4e38f; bi[f] = 0; }
        for (int ii = 0; ii < 16; ++ii) {
            int code = ii * 64 + lane;
            const float4* cp = (const float4*)(cbase + (size_t)code * 64);
            float dd[4][4];
            #pragma unroll
            for (int f = 0; f < 4; ++f)
                #pragma unroll
                for (int j = 0; j < 4; ++j) dd[f][j] = 0.f;
            #pragma unroll
            for (int q = 0; q < 16; ++q) {
                float4 cv = cp[q];
                #pragma unroll
                for (int f = 0; f < 4; ++f) {
                    float4 za = *(const float4*)&zsh[wv][f][4 * q];
                    dd[f][0] = fmaf(za.x, cv.x, dd[f][0]);
                    dd[f][1] = fmaf(za.y, cv.y, dd[f][1]);
                    dd[f][2] = fmaf(za.z, cv.z, dd[f][2]);
                    dd[f][3] = fmaf(za.w, cv.w, dd[f][3]);
                }
            }
            float cc0 = ccb[code];
            #pragma unroll
            for (int f = 0; f < 4; ++f) {
                float s = fmaf(-2.0f, (dd[f][0] + dd[f][1]) + (dd[f][2] + dd[f][3]), cc0);
                if (s < bv[f]) { bv[f] = s; bi[f] = code; }
            }
        }
        #pragma unroll
        for (int ddp = 1; ddp < 64; ddp <<= 1) {
            #pragma unroll
            for (int f = 0; f < 4; ++f) {
                float ov = __shfl_xor(bv[f], ddp, 64);
                int   oi = __shfl_xor(bi[f], ddp, 64);
                if (ov < bv[f] || (ov == bv[f] && oi < bi[f])) { bv[f] = ov; bi[f] = oi; }
            }
        }
        if (lane == 0) {
            #pragma unroll
            for (int f = 0; f < 4; ++f)
                out[((size_t)cb * 64 + bf_[f]) * T + tf_[f]] = bi[f];
        }
    }
}

extern "C" void kernel_launch(void* const* d_in, const int* in_sizes, int n_in,
                              void* d_out, int out_size, void* d_ws, size_t ws_size,
                              hipStream_t stream)
{
    const float* x   = (const float*)d_in[0];
    const float* w0  = (const float*)d_in[1];
    const float* b0  = (const float*)d_in[2];
    const float* w1  = (const float*)d_in[3];
    const float* b1  = (const float*)d_in[4];
    const float* w2  = (const float*)d_in[5];
    const float* b2  = (const float*)d_in[6];
    const float* w3  = (const float*)d_in[7];
    const float* b3  = (const float*)d_in[8];
    const float* wq  = (const float*)d_in[9];
    const float* bq  = (const float*)d_in[10];
    const float* cbs = (const float*)d_in[11];
    int* out = (int*)d_out;

    // two 98,304,000-byte regions (proven footprint)
    char* r1 = (char*)d_ws;
    char* r2 = r1 + 98304000;
    float* H1 = (float*)r2;               // [64][6000][64]  (phase-split)
    float* H2 = (float*)r1;               // [64][6000][64]
    float* H3 = (float*)r2;               // [64][2000][64]  (over dead H1)
    float* z  = (float*)(r2 + 32768000);  // [64][128][2000] fp32

    // weight fragments in d_out (dead until vq_mfma rewrites it)
    short* wf1 = (short*)d_out;           // 12288 shorts
    short* wf2 = wf1 + 12288;             // 49152
    short* wf3 = wf1 + 61440;             // 86016
    short* wf4 = wf1 + 147456;            // 172032 -> ends at 319488 shorts

    // VQ prep data in r1 (free after conv3 consumes H2)
    short* cbf   = (short*)r1;
    float* cc    = (float*)(r1 + 524288);
    int*   cnt   = (int*)(r1 + 540000);
    int*   list0 = (int*)(r1 + 1000000);
    int*   list1 = (int*)(r1 + 2100000);

    // weight prep (reads inputs only)
    wprep3_ps_kernel<16, 32><<<1, 32, 0, stream>>>(w1, wf1);
    wprep3_ps_kernel<32, 64><<<1, 64, 0, stream>>>(w2, wf2);
    wprep3_kernel<64, 64, 7><<<1, 64, 0, stream>>>(w3, wf3);
    wprep3_kernel<64, 128, 7><<<1, 128, 0, stream>>>(wq, wf4);

    // fused conv0+conv1: x -> H1 (phase-split), H0 recomputed in-kernel
    conv01_kernel<<<dim3(94, 64), 256, 0, stream>>>(x, w0, b0, wf1, b1, H1);
    // conv2: H1 -> H2, stride-1 K=4 over 64ch, t-major out (NTL=2, r21 config)
    conv_mfma3_kernel<1, 64, 64, 2, 4, 3, 0><<<dim3(47, 64), 256, 0, stream>>>(
        H1, wf2, b2, H2, 6000, 6000);
    // conv3: H2 -> H3, stride 3, K=7, t-major out
    conv_mfma3_kernel<3, 64, 64, 1, 7, 6, 0><<<dim3(32, 64), 256, 0, stream>>>(
        H2, wf3, b3, H3, 6000, 2000);

    // VQ prep into r1 (H2 now dead)
    vq_prep_kernel<<<8, 256, 0, stream>>>(cbs, cc, cbf);
    zero_cnt_kernel<<<1, 64, 0, stream>>>(cnt);

    // conv4: H3 -> z (fp32 [co][t]), stride 1, K=7 (NTL=2, r21 config)
    conv_mfma3_kernel<1, 64, 128, 2, 7, 6, 2><<<dim3(16, 64), 256, 0, stream>>>(
        H3, wf4, bq, z, 2000, 2000);

    // VQ: MFMA scores + per-cb flag lists, then 4-way shared exact rescore
    vq_mfma_kernel<<<dim3(16, 2, 64), 256, 0, stream>>>(z, cbf, cc, out, cnt, list0, list1);
    vq_rescore_kernel<<<dim3(512, 2), 256, 0, stream>>>(H3, wq, bq, cbs, cc, cnt, list0, list1, out);
}